// Round 24
// baseline (69.996 us; speedup 1.0000x reference)
//
#include <hip/hip_runtime.h>

#define HH 64
#define WWD 64
#define CIN 256
#define OUTC 256
#define BB 4
#define KK 9
#define NSO 9    // offset-conv K-steps per q (one chunk, all 9 taps)
#define QOFF 8   // offset-conv K-split partials (one per chunk)
#define NIT3 12  // main loop per q-half: 4 chunks * 3 iterations of 3 taps
#define WROWS 8
#define WPIX 512 // 8 rows x 64 cols

typedef __attribute__((ext_vector_type(8))) short short8;
typedef __attribute__((ext_vector_type(4))) unsigned short ushort4v;
typedef __attribute__((ext_vector_type(4))) float float4v;
typedef _Float16 half8 __attribute__((ext_vector_type(8)));

__device__ __forceinline__ short f2bf(float f) {
    unsigned u = __builtin_bit_cast(unsigned, f);
    u += 0x7fffu + ((u >> 16) & 1u);
    return (short)(u >> 16);
}
// v_cvt_pkrtz_f16_f32: dst = [hi:f16(b) | lo:f16(a)]
__device__ __forceinline__ unsigned cvtpkh(float a, float b) {
    unsigned r;
    asm("v_cvt_pkrtz_f16_f32 %0, %1, %2" : "=v"(r) : "v"(a), "v"(b));
    return r;
}
__device__ __forceinline__ half8 pack8h(const float* a) {
    union { half8 h; unsigned u[4]; } r;
    r.u[0] = cvtpkh(a[0], a[1]); r.u[1] = cvtpkh(a[2], a[3]);
    r.u[2] = cvtpkh(a[4], a[5]); r.u[3] = cvtpkh(a[6], a[7]);
    return r.h;
}
__device__ __forceinline__ unsigned short f2hbits(float f) {
    return (unsigned short)__builtin_bit_cast(unsigned short, (_Float16)f);
}
__device__ __forceinline__ _Float16 h_from_bits(unsigned short u) {
    return __builtin_bit_cast(_Float16, u);
}
// floor(s/9) for s in [0,72)
__device__ __forceinline__ int div9(int s) { return (s * 57) >> 9; }

// ---------------------------------------------------------------------------
// Kernel P: pack both weight tensors to f16. blocks 0..2303 -> wt2,
// blocks 2304..2591 -> wo2. CHANNEL-major K: s=chunk*9+tap.
// ---------------------------------------------------------------------------
__global__ __launch_bounds__(256) void k_packs(const float* __restrict__ w,
                                               const float* __restrict__ w_off,
                                               unsigned short* __restrict__ wt2,
                                               unsigned short* __restrict__ wo2) {
    const int bid = blockIdx.x;
    if (bid < 2304) {
        int gid = bid * 256 + threadIdx.x;      // < 72*256*32
        int kk = gid & 31;
        int o  = (gid >> 5) & 255;
        int s  = gid >> 13;
        int chunk = div9(s), tap = s - 9 * chunk;
        int c = (chunk << 5) + kk;
        wt2[gid] = f2hbits(w[(o * CIN + c) * 9 + tap]);
    } else {
        int gid = (bid - 2304) * 256 + threadIdx.x;   // < 72*32*32
        int kk = gid & 31;
        int m  = (gid >> 5) & 31;
        int s  = gid >> 10;
        int chunk = div9(s), tap = s - 9 * chunk;
        int c = (chunk << 5) + kk;
        wo2[gid] = (m < 27) ? f2hbits(w_off[(m * CIN + c) * 9 + tap])
                            : (unsigned short)0;
    }
}

// ---------------------------------------------------------------------------
// Kernel 1: offset conv via f16 MFMA, 8-way K-split (one chunk per q).
// grid 2048 (XCD-swizzled: each XCD gets 32 h-rows of one b, all 8 q).
// ---------------------------------------------------------------------------
__global__ __launch_bounds__(256) void k_off_mfma(const float* __restrict__ x,
                                                  const unsigned short* __restrict__ wo2,
                                                  float* __restrict__ om_part) {
    const int wgid = blockIdx.x;                        // 0..2047
    const int swz  = ((wgid & 7) << 8) + (wgid >> 3);   // bijective XCD chunk
    const int q = swz & 7;                              // chunk 0..7
    const int h = (swz >> 3) & 63;
    const int b = swz >> 9;
    const int tid = threadIdx.x;
    const int lane = tid & 63;
    const int wid  = tid >> 6;

    __shared__ _Float16 S[2][4][64][8];

    const int px_t = tid & 63;
    const int g    = tid >> 6;
    const float* xb = x + ((size_t)b << 20);

    float gv[8];
    auto ISSUE = [&](int s2) {
        const int chunk = div9(s2), tap = s2 - 9 * chunk;
        const int gy = h + tap / 3 - 1;
        const int gx = px_t + tap % 3 - 1;
        const bool ok = ((unsigned)gy < 64u) && ((unsigned)gx < 64u);
        const float* xc = xb + (((chunk << 5) + (g << 3)) << 12) + (gy << 6) + gx;
#pragma unroll
        for (int j = 0; j < 8; ++j)
            gv[j] = ok ? xc[(size_t)j << 12] : 0.f;
    };
    auto CONSUME = [&](int buf) {
        *(half8*)(&S[buf][g][px_t][0]) = pack8h(gv);
    };

    const int arow = lane & 15;
    const int akk  = (lane >> 4) << 3;
    const int bpx  = lane & 15;
    const int bg   = lane >> 4;

    float4v acc0 = {0.f, 0.f, 0.f, 0.f};
    float4v acc1 = {0.f, 0.f, 0.f, 0.f};

    const int s0 = q * NSO;
    ISSUE(s0); CONSUME(0); ISSUE(s0 + 1);
    const unsigned short* abase = wo2 + (size_t)s0 * 1024 + arow * 32 + akk;
    half8 aC0 = *(const half8*)(abase);
    half8 aC1 = *(const half8*)(abase + 512);
    __syncthreads();

#pragma unroll 1
    for (int ls = 0; ls < NSO; ++ls) {
        const int lsn = (ls + 1 < NSO) ? ls + 1 : ls;
        const unsigned short* an = wo2 + (size_t)(s0 + lsn) * 1024 + arow * 32 + akk;
        half8 aN0 = *(const half8*)(an);
        half8 aN1 = *(const half8*)(an + 512);

        half8 bf = *(const half8*)(&S[ls & 1][bg][(wid << 4) + bpx][0]);
        acc0 = __builtin_amdgcn_mfma_f32_16x16x32_f16(aC0, bf, acc0, 0, 0, 0);
        acc1 = __builtin_amdgcn_mfma_f32_16x16x32_f16(aC1, bf, acc1, 0, 0, 0);

        if (ls < NSO - 1) {
            CONSUME((ls + 1) & 1);
            if (ls + 2 < NSO) ISSUE(s0 + ls + 2);
        }
        aC0 = aN0; aC1 = aN1;
        __syncthreads();
    }

    const int pxo = (wid << 4) + bpx;
    float* ob = om_part + (((size_t)(q * BB + b) * 27) << 12) + (h << 6) + pxo;
#pragma unroll
    for (int r = 0; r < 4; ++r) {
        const int m0 = ((lane >> 4) << 2) + r;
        ob[(size_t)m0 << 12] = acc0[r];
        const int m1 = 16 + m0;
        if (m1 < 27) ob[(size_t)m1 << 12] = acc1[r];
    }
}

// ---------------------------------------------------------------------------
// Kernel 2: deformable conv partial (K-split in 2) via f16 MFMA, raw sums.
// flat grid 512 (XCD-swizzled), block 512 (8 waves): M=256 x N=64 px.
// q=0 -> raw sums into d_out; q=1 -> raw sums into part1 (ws).
// Window: 8 rows x 64 cols x 32ch f16 (32 KB), swizzled. 3 taps/iteration.
// Sampling interpolation in PACKED f16 (half8).
// ---------------------------------------------------------------------------
__global__ __launch_bounds__(512) void k_main(
    const float* __restrict__ x, const float* __restrict__ om_part,
    const float* __restrict__ b_off, const unsigned short* __restrict__ wt2,
    float* __restrict__ outr, float* __restrict__ part1) {

    const int wgid = blockIdx.x;                       // 0..511
    const int swz  = ((wgid & 7) << 6) + (wgid >> 3);  // XCD-contiguous
    const int q = swz & 1;                             // K half
    const int h = (swz >> 1) & 63;
    const int b = swz >> 7;
    const int tid  = threadIdx.x;
    const int lane = tid & 63;
    const int wid  = tid >> 6;

    __shared__ ushort4v sidx2[576];        // packed corners or sentinel
    __shared__ ushort4v sw4[576];          // f16 corner weights (mask folded)
    __shared__ _Float16 S[2][3][4][64][8]; // [buf][tap-in-triple][g][px][8k]
    __shared__ _Float16 xw[WPIX * 32];     // [pix 512][32ch] f16, swizzled

    // ---- stage 0: bilinear params per (tap,px) -----------------------------
    for (int j = tid; j < 576; j += 512) {
        const int k  = j >> 6;
        const int px = j & 63;
        const int sp = (h << 6) + px;
        float oy = b_off[k], ox = b_off[k + KK], mz = b_off[k + 2 * KK];
#pragma unroll
        for (int qq = 0; qq < QOFF; ++qq) {
            const float* bp = om_part + (size_t)((qq * BB + b) * 27) * 4096 + sp;
            oy += bp[k * 4096];
            ox += bp[(k + KK) * 4096];
            mz += bp[(k + 2 * KK) * 4096];
        }
        const float mask = 1.f / (1.f + expf(-mz));
        const float py  = (float)h  - 1.f + (float)(k / 3) + oy;
        const float pxc = (float)px - 1.f + (float)(k % 3) + ox;
        const float y0f = floorf(py), x0f = floorf(pxc);
        const float ly = py - y0f, lx = pxc - x0f;
        const int y0 = (int)y0f, x0 = (int)x0f;

        float w00, w01, w10, w11;
        {
            bool v = (y0 >= 0) && (y0 < HH) && (x0 >= 0) && (x0 < WWD);
            w00 = v ? (1.f - ly) * (1.f - lx) * mask : 0.f;
        }
        {
            bool v = (y0 >= 0) && (y0 < HH) && (x0 + 1 < WWD) && (x0 + 1 >= 0);
            w01 = v ? (1.f - ly) * lx * mask : 0.f;
        }
        {
            bool v = (y0 + 1 >= 0) && (y0 + 1 < HH) && (x0 >= 0) && (x0 < WWD);
            w10 = v ? ly * (1.f - lx) * mask : 0.f;
        }
        {
            bool v = (y0 + 1 >= 0) && (y0 + 1 < HH) && (x0 + 1 >= 0) && (x0 + 1 < WWD);
            w11 = v ? ly * lx * mask : 0.f;
        }
        const int cy0 = min(max(y0, 0), 63),     cy1 = min(max(y0 + 1, 0), 63);
        const int cx0 = min(max(x0, 0), 63),     cx1 = min(max(x0 + 1, 0), 63);
        const int li0 = cy0 - (h - 3),           li1 = cy1 - (h - 3);
        ushort4v pv;
        if ((unsigned)li0 < (unsigned)WROWS && (unsigned)li1 < (unsigned)WROWS) {
            const int p00 = (li0 << 6) + cx0, p01 = (li0 << 6) + cx1;
            const int p10 = (li1 << 6) + cx0, p11 = (li1 << 6) + cx1;
            pv.x = (unsigned short)((p00 << 6) | ((p00 + (p00 >> 2)) & 3));
            pv.y = (unsigned short)((p01 << 6) | ((p01 + (p01 >> 2)) & 3));
            pv.z = (unsigned short)((p10 << 6) | ((p10 + (p10 >> 2)) & 3));
            pv.w = (unsigned short)((p11 << 6) | ((p11 + (p11 >> 2)) & 3));
        } else {                       // window miss -> global fallback
            pv.x = 0xFFFFu;
            pv.y = (unsigned short)(y0 + 32);
            pv.z = (unsigned short)(x0 + 32);
            pv.w = 0;
        }
        ushort4v wv;
        wv.x = f2hbits(w00);
        wv.y = f2hbits(w01);
        wv.z = f2hbits(w10);
        wv.w = f2hbits(w11);
        sidx2[j] = pv;
        sw4[j]   = wv;
    }

    const float* xb = x + ((size_t)b << 20);

    // ---- window staging (sync): [pix 512][32ch] f16, swizzled --------------
    auto STAGE = [&](int chunk) {
#pragma unroll
        for (int r4 = 0; r4 < 4; ++r4) {
            const int t   = r4 * 512 + tid;          // 0..2047
            const int g   = t >> 9;                  // 0..3 (8-ch group)
            const int pix = t & 511;
            const int wr  = pix >> 6, col = pix & 63;
            const int gro = (min(max(h - 3 + wr, 0), 63) << 6) + col;
            const float* xc = xb + ((size_t)((chunk << 5) + (g << 3)) << 12) + gro;
            float a[8];
#pragma unroll
            for (int j = 0; j < 8; ++j) a[j] = xc[(size_t)j << 12];
            const int pos = (g + pix + (pix >> 2)) & 3;
            *(half8*)&xw[pix * 32 + pos * 8] = pack8h(a);
        }
    };

    // ---- sampling task: 8 channels, packed-f16 interpolation ---------------
    auto TASK = [&](int c2, int sub2, int t, int buf2) {
        const int tp   = t >> 8;                 // tap within triple (0..2)
        const int slot = t & 255;
        const int g  = slot >> 6;
        const int px = slot & 63;
        const int tap = sub2 * 3 + tp;           // local tap 0..8
        const int j = (tap << 6) + px;
        const ushort4v sv = sidx2[j];
        const ushort4v wv = sw4[j];
        if (sv.x != 0xFFFFu) {
            const int o0 = ((sv.x & 0xFFC0u) >> 1) + (((sv.x + g) & 3u) << 3);
            const int o1 = ((sv.y & 0xFFC0u) >> 1) + (((sv.y + g) & 3u) << 3);
            const int o2 = ((sv.z & 0xFFC0u) >> 1) + (((sv.z + g) & 3u) << 3);
            const int o3 = ((sv.w & 0xFFC0u) >> 1) + (((sv.w + g) & 3u) << 3);
            const half8 c00 = *(const half8*)&xw[o0];
            const half8 c01 = *(const half8*)&xw[o1];
            const half8 c10 = *(const half8*)&xw[o2];
            const half8 c11 = *(const half8*)&xw[o3];
            half8 a8 = c00 * h_from_bits(wv.x) + c01 * h_from_bits(wv.y)
                     + c10 * h_from_bits(wv.z) + c11 * h_from_bits(wv.w);
            *(half8*)&S[buf2][tp][g][px][0] = a8;
        } else {                             // global fallback (rare)
            const float w00 = (float)h_from_bits(wv.x);
            const float w01 = (float)h_from_bits(wv.y);
            const float w10 = (float)h_from_bits(wv.z);
            const float w11 = (float)h_from_bits(wv.w);
            const int y0 = (int)sv.y - 32, x0 = (int)sv.z - 32;
            const int cy0 = min(max(y0, 0), 63), cy1 = min(max(y0 + 1, 0), 63);
            const int cx0 = min(max(x0, 0), 63), cx1 = min(max(x0 + 1, 0), 63);
            const int i00 = (cy0 << 6) + cx0, i01 = (cy0 << 6) + cx1;
            const int i10 = (cy1 << 6) + cx0, i11 = (cy1 << 6) + cx1;
            const float* xc = xb + ((size_t)((c2 << 5) + (g << 3)) << 12);
            float a[8];
#pragma unroll
            for (int j2 = 0; j2 < 8; ++j2) {
                a[j2] = w00 * xc[i00] + w01 * xc[i01]
                      + w10 * xc[i10] + w11 * xc[i11];
                xc += 4096;
            }
            *(half8*)&S[buf2][tp][g][px][0] = pack8h(a);
        }
    };
    // 768 tasks over 512 threads: every thread one, waves 0-3 a second.
    auto SAMPLE3 = [&](int c2, int sub2, int buf2) {
        TASK(c2, sub2, tid, buf2);
        if (tid < 256) TASK(c2, sub2, 512 + tid, buf2);
    };

    // A-frag: wave wid owns rows wid*32..+31; lane row=(lane&15), k=(lane>>4)*8+j
    const unsigned short* wbase = wt2 + ((wid * 32 + (lane & 15)) << 5)
                                      + ((lane >> 4) << 3);
    const int bpx = lane & 15;
    const int bg  = lane >> 4;

    float4v acc[2][4];
#pragma unroll
    for (int mt = 0; mt < 2; ++mt)
#pragma unroll
        for (int nt = 0; nt < 4; ++nt) acc[mt][nt] = (float4v){0.f, 0.f, 0.f, 0.f};

    const int c0 = q * 4;                 // this block's chunk range [c0, c0+4)

    __syncthreads();             // params ready
    STAGE(c0);
    __syncthreads();             // window chunk c0 ready
    SAMPLE3(c0, 0, 0);           // taps 0,1,2 -> S[0]
    __syncthreads();             // S[0] ready

    // ---- main loop: 12 iterations (3 taps each) ----------------------------
    int c = c0, sub = 0;
#pragma unroll 1
    for (int it = 0; it < NIT3; ++it) {
        const int sbase = c * 9 + sub * 3;
        const half8 a00 = *(const half8*)(wbase + (size_t)sbase * 8192);
        const half8 a01 = *(const half8*)(wbase + (size_t)sbase * 8192 + 512);
        const half8 a10 = *(const half8*)(wbase + (size_t)(sbase + 1) * 8192);
        const half8 a11 = *(const half8*)(wbase + (size_t)(sbase + 1) * 8192 + 512);
        const half8 a20 = *(const half8*)(wbase + (size_t)(sbase + 2) * 8192);
        const half8 a21 = *(const half8*)(wbase + (size_t)(sbase + 2) * 8192 + 512);

        const int buf = it & 1;
        __builtin_amdgcn_s_setprio(1);
        {
            const _Float16* Sb = &S[buf][0][bg][bpx][0];
            half8 b0 = *(const half8*)(Sb);
            half8 b1 = *(const half8*)(Sb + 128);
            half8 b2 = *(const half8*)(Sb + 256);
            half8 b3 = *(const half8*)(Sb + 384);
            acc[0][0] = __builtin_amdgcn_mfma_f32_16x16x32_f16(a00, b0, acc[0][0], 0, 0, 0);
            acc[0][1] = __builtin_amdgcn_mfma_f32_16x16x32_f16(a00, b1, acc[0][1], 0, 0, 0);
            acc[0][2] = __builtin_amdgcn_mfma_f32_16x16x32_f16(a00, b2, acc[0][2], 0, 0, 0);
            acc[0][3] = __builtin_amdgcn_mfma_f32_16x16x32_f16(a00, b3, acc[0][3], 0, 0, 0);
            acc[1][0] = __builtin_amdgcn_mfma_f32_16x16x32_f16(a01, b0, acc[1][0], 0, 0, 0);
            acc[1][1] = __builtin_amdgcn_mfma_f32_16x16x32_f16(a01, b1, acc[1][1], 0, 0, 0);
            acc[1][2] = __builtin_amdgcn_mfma_f32_16x16x32_f16(a01, b2, acc[1][2], 0, 0, 0);
            acc[1][3] = __builtin_amdgcn_mfma_f32_16x16x32_f16(a01, b3, acc[1][3], 0, 0, 0);
        }
        {
            const _Float16* Sb = &S[buf][1][bg][bpx][0];
            half8 b0 = *(const half8*)(Sb);
            half8 b1 = *(const half8*)(Sb + 128);
            half8 b2 = *(const half8*)(Sb + 256);
            half8 b3 = *(const half8*)(Sb + 384);
            acc[0][0] = __builtin_amdgcn_mfma_f32_16x16x32_f16(a10, b0, acc[0][0], 0, 0, 0);
            acc[0][1] = __builtin_amdgcn_mfma_f32_16x16x32_f16(a10, b1, acc[0][1], 0, 0, 0);
            acc[0][2] = __builtin_amdgcn_mfma_f32_16x16x32_f16(a10, b2, acc[0][2], 0, 0, 0);
            acc[0][3] = __builtin_amdgcn_mfma_f32_16x16x32_f16(a10, b3, acc[0][3], 0, 0, 0);
            acc[1][0] = __builtin_amdgcn_mfma_f32_16x16x32_f16(a11, b0, acc[1][0], 0, 0, 0);
            acc[1][1] = __builtin_amdgcn_mfma_f32_16x16x32_f16(a11, b1, acc[1][1], 0, 0, 0);
            acc[1][2] = __builtin_amdgcn_mfma_f32_16x16x32_f16(a11, b2, acc[1][2], 0, 0, 0);
            acc[1][3] = __builtin_amdgcn_mfma_f32_16x16x32_f16(a11, b3, acc[1][3], 0, 0, 0);
        }
        {
            const _Float16* Sb = &S[buf][2][bg][bpx][0];
            half8 b0 = *(const half8*)(Sb);
            half8 b1 = *(const half8*)(Sb + 128);
            half8 b2 = *(const half8*)(Sb + 256);
            half8 b3 = *(const half8*)(Sb + 384);
            acc[0][0] = __builtin_amdgcn_mfma_f32_16x16x32_f16(a20, b0, acc[0][0], 0, 0, 0);
            acc[0][1] = __builtin_amdgcn_mfma_f32_16x16x32_f16(a20, b1, acc[0][1], 0, 0, 0);
            acc[0][2] = __builtin_amdgcn_mfma_f32_16x16x32_f16(a20, b2, acc[0][2], 0, 0, 0);
            acc[0][3] = __builtin_amdgcn_mfma_f32_16x16x32_f16(a20, b3, acc[0][3], 0, 0, 0);
            acc[1][0] = __builtin_amdgcn_mfma_f32_16x16x32_f16(a21, b0, acc[1][0], 0, 0, 0);
            acc[1][1] = __builtin_amdgcn_mfma_f32_16x16x32_f16(a21, b1, acc[1][1], 0, 0, 0);
            acc[1][2] = __builtin_amdgcn_mfma_f32_16x16x32_f16(a21, b2, acc[1][2], 0, 0, 0);
            acc[1][3] = __builtin_amdgcn_mfma_f32_16x16x32_f16(a21, b3, acc[1][3], 0, 0, 0);
        }
        __builtin_amdgcn_s_setprio(0);

        if (it + 1 < NIT3) {
            int subn = sub + 1, cn = c;
            if (subn == 3) { subn = 0; cn = c + 1; }
            if (subn == 0) {                     // next iter samples new chunk
                STAGE(cn);
                __syncthreads();                 // window cn ready
            }
            SAMPLE3(cn, subn, (it + 1) & 1);
            c = cn; sub = subn;
        }
        __syncthreads();
    }

    // ---- epilogue: raw partial sums; D layout col=lane&15, row=(lane>>4)*4+r
    const int r4 = lane >> 4;
    float* ob = (q == 0 ? outr : part1) + (((size_t)b * 256) << 12) + (h << 6);
#pragma unroll
    for (int mt = 0; mt < 2; ++mt)
#pragma unroll
        for (int nt = 0; nt < 4; ++nt) {
            const int px = nt * 16 + bpx;
#pragma unroll
            for (int r = 0; r < 4; ++r) {
                const int o = wid * 32 + mt * 16 + r4 * 4 + r;
                ob[((size_t)o << 12) + px] = acc[mt][nt][r];
            }
        }
}

// ---------------------------------------------------------------------------
// Kernel 3: sum partials + bias + BN + ReLU, in-place on d_out. float4.
// ---------------------------------------------------------------------------
__global__ __launch_bounds__(256) void k_bn(const float* __restrict__ part1,
                                            const float* __restrict__ bias,
                                            const float* __restrict__ gamma,
                                            const float* __restrict__ beta,
                                            const float* __restrict__ rmean,
                                            const float* __restrict__ rvar,
                                            float* __restrict__ out) {
    const int NTOT4 = BB * OUTC * 4096 / 4;          // 1,048,576 float4
    int i = blockIdx.x * 256 + threadIdx.x;
    const int stride = gridDim.x * 256;
#pragma unroll 1
    for (; i < NTOT4; i += stride) {
        const int e0 = i << 2;
        const int o  = (e0 >> 12) & 255;             // channel (wave-uniform)
        const float inv = gamma[o] * rsqrtf(rvar[o] + 1e-5f);
        const float sh  = beta[o] - rmean[o] * inv + bias[o] * inv;
        float4 a = ((const float4*)out)[i];
        float4 p = ((const float4*)part1)[i];
        float4 v;
        v.x = fmaxf((a.x + p.x) * inv + sh, 0.f);
        v.y = fmaxf((a.y + p.y) * inv + sh, 0.f);
        v.z = fmaxf((a.z + p.z) * inv + sh, 0.f);
        v.w = fmaxf((a.w + p.w) * inv + sh, 0.f);
        ((float4*)out)[i] = v;
    }
}

// ---------------------------------------------------------------------------
extern "C" void kernel_launch(void* const* d_in, const int* in_sizes, int n_in,
                              void* d_out, int out_size, void* d_ws, size_t ws_size,
                              hipStream_t stream) {
    const float* x     = (const float*)d_in[0];
    const float* w_off = (const float*)d_in[1];
    const float* b_off = (const float*)d_in[2];
    const float* w     = (const float*)d_in[3];
    const float* bias  = (const float*)d_in[4];
    const float* gamma = (const float*)d_in[5];
    const float* beta  = (const float*)d_in[6];
    const float* rmean = (const float*)d_in[7];
    const float* rvar  = (const float*)d_in[8];
    float* out = (float*)d_out;

    float* om_part = (float*)d_ws;                                  // 8*4*27*4096 f32
    unsigned short* wt2 = (unsigned short*)(om_part + QOFF * BB * 27 * 4096);
    unsigned short* wo2 = wt2 + 72 * 256 * 32;                      // 72*32*32 f16
    float* part1   = (float*)(wo2 + 72 * 32 * 32);                  // 4*256*4096 f32

    k_packs<<<2592, 256, 0, stream>>>(w, w_off, wt2, wo2);
    k_off_mfma<<<2048, 256, 0, stream>>>(x, wo2, om_part);
    k_main<<<512, 512, 0, stream>>>(x, om_part, b_off, wt2, out, part1);
    k_bn<<<2048, 256, 0, stream>>>(part1, bias, gamma, beta, rmean, rvar, out);
}

// Round 25
// 66.374 us; speedup vs baseline: 1.0546x; 1.0546x over previous
//
#include <hip/hip_runtime.h>

#define HH 64
#define WWD 64
#define CIN 256
#define OUTC 256
#define BB 4
#define KK 9
#define NSO2 18  // offset-conv K-steps per q-quarter
#define QOFF 4   // offset-conv K-split partials
#define NIT3 12  // main loop per q-half: 4 chunks * 3 iterations of 3 taps
#define WROWS 8
#define WPIX 512 // 8 rows x 64 cols

typedef __attribute__((ext_vector_type(8))) short short8;
typedef __attribute__((ext_vector_type(4))) unsigned short ushort4v;
typedef __attribute__((ext_vector_type(4))) float float4v;
typedef _Float16 half8 __attribute__((ext_vector_type(8)));

__device__ __forceinline__ short f2bf(float f) {
    unsigned u = __builtin_bit_cast(unsigned, f);
    u += 0x7fffu + ((u >> 16) & 1u);
    return (short)(u >> 16);
}
// v_cvt_pkrtz_f16_f32: dst = [hi:f16(b) | lo:f16(a)]
__device__ __forceinline__ unsigned cvtpkh(float a, float b) {
    unsigned r;
    asm("v_cvt_pkrtz_f16_f32 %0, %1, %2" : "=v"(r) : "v"(a), "v"(b));
    return r;
}
__device__ __forceinline__ half8 pack8h(const float* a) {
    union { half8 h; unsigned u[4]; } r;
    r.u[0] = cvtpkh(a[0], a[1]); r.u[1] = cvtpkh(a[2], a[3]);
    r.u[2] = cvtpkh(a[4], a[5]); r.u[3] = cvtpkh(a[6], a[7]);
    return r.h;
}
__device__ __forceinline__ unsigned short f2hbits(float f) {
    return (unsigned short)__builtin_bit_cast(unsigned short, (_Float16)f);
}
__device__ __forceinline__ _Float16 h_from_bits(unsigned short u) {
    return __builtin_bit_cast(_Float16, u);
}
// floor(s/9) for s in [0,72)
__device__ __forceinline__ int div9(int s) { return (s * 57) >> 9; }

// ---------------------------------------------------------------------------
// Kernel P: pack both weight tensors to f16. blocks 0..2303 -> wt2,
// blocks 2304..2591 -> wo2. CHANNEL-major K: s=chunk*9+tap.
// ---------------------------------------------------------------------------
__global__ __launch_bounds__(256) void k_packs(const float* __restrict__ w,
                                               const float* __restrict__ w_off,
                                               unsigned short* __restrict__ wt2,
                                               unsigned short* __restrict__ wo2) {
    const int bid = blockIdx.x;
    if (bid < 2304) {
        int gid = bid * 256 + threadIdx.x;      // < 72*256*32
        int kk = gid & 31;
        int o  = (gid >> 5) & 255;
        int s  = gid >> 13;
        int chunk = div9(s), tap = s - 9 * chunk;
        int c = (chunk << 5) + kk;
        wt2[gid] = f2hbits(w[(o * CIN + c) * 9 + tap]);
    } else {
        int gid = (bid - 2304) * 256 + threadIdx.x;   // < 72*32*32
        int kk = gid & 31;
        int m  = (gid >> 5) & 31;
        int s  = gid >> 10;
        int chunk = div9(s), tap = s - 9 * chunk;
        int c = (chunk << 5) + kk;
        wo2[gid] = (m < 27) ? f2hbits(w_off[(m * CIN + c) * 9 + tap])
                            : (unsigned short)0;
    }
}

// ---------------------------------------------------------------------------
// Kernel 1: offset conv via f16 MFMA, 4-way K-split. grid 1024, XCD-swizzled.
// ---------------------------------------------------------------------------
__global__ __launch_bounds__(256) void k_off_mfma(const float* __restrict__ x,
                                                  const unsigned short* __restrict__ wo2,
                                                  float* __restrict__ om_part) {
    const int wgid = blockIdx.x;                        // 0..1023
    const int swz  = ((wgid & 7) << 7) + (wgid >> 3);   // bijective XCD chunk
    const int q = swz & 3;
    const int h = (swz >> 2) & 63;
    const int b = swz >> 8;
    const int tid = threadIdx.x;
    const int lane = tid & 63;
    const int wid  = tid >> 6;

    __shared__ _Float16 S[2][4][64][8];

    const int px_t = tid & 63;
    const int g    = tid >> 6;
    const float* xb = x + ((size_t)b << 20);

    float gv[8];
    auto ISSUE = [&](int s2) {
        const int chunk = div9(s2), tap = s2 - 9 * chunk;
        const int gy = h + tap / 3 - 1;
        const int gx = px_t + tap % 3 - 1;
        const bool ok = ((unsigned)gy < 64u) && ((unsigned)gx < 64u);
        const float* xc = xb + (((chunk << 5) + (g << 3)) << 12) + (gy << 6) + gx;
#pragma unroll
        for (int j = 0; j < 8; ++j)
            gv[j] = ok ? xc[(size_t)j << 12] : 0.f;
    };
    auto CONSUME = [&](int buf) {
        *(half8*)(&S[buf][g][px_t][0]) = pack8h(gv);
    };

    const int arow = lane & 15;
    const int akk  = (lane >> 4) << 3;
    const int bpx  = lane & 15;
    const int bg   = lane >> 4;

    float4v acc0 = {0.f, 0.f, 0.f, 0.f};
    float4v acc1 = {0.f, 0.f, 0.f, 0.f};

    const int s0 = q * NSO2;
    ISSUE(s0); CONSUME(0); ISSUE(s0 + 1);
    const unsigned short* abase = wo2 + (size_t)s0 * 1024 + arow * 32 + akk;
    half8 aC0 = *(const half8*)(abase);
    half8 aC1 = *(const half8*)(abase + 512);
    __syncthreads();

#pragma unroll 1
    for (int ls = 0; ls < NSO2; ++ls) {
        const int lsn = (ls + 1 < NSO2) ? ls + 1 : ls;
        const unsigned short* an = wo2 + (size_t)(s0 + lsn) * 1024 + arow * 32 + akk;
        half8 aN0 = *(const half8*)(an);
        half8 aN1 = *(const half8*)(an + 512);

        half8 bf = *(const half8*)(&S[ls & 1][bg][(wid << 4) + bpx][0]);
        acc0 = __builtin_amdgcn_mfma_f32_16x16x32_f16(aC0, bf, acc0, 0, 0, 0);
        acc1 = __builtin_amdgcn_mfma_f32_16x16x32_f16(aC1, bf, acc1, 0, 0, 0);

        if (ls < NSO2 - 1) {
            CONSUME((ls + 1) & 1);
            if (ls + 2 < NSO2) ISSUE(s0 + ls + 2);
        }
        aC0 = aN0; aC1 = aN1;
        __syncthreads();
    }

    const int pxo = (wid << 4) + bpx;
    float* ob = om_part + (((size_t)(q * BB + b) * 27) << 12) + (h << 6) + pxo;
#pragma unroll
    for (int r = 0; r < 4; ++r) {
        const int m0 = ((lane >> 4) << 2) + r;
        ob[(size_t)m0 << 12] = acc0[r];
        const int m1 = 16 + m0;
        if (m1 < 27) ob[(size_t)m1 << 12] = acc1[r];
    }
}

// ---------------------------------------------------------------------------
// Kernel 2: deformable conv partial (K-split in 2) via f16 MFMA.
// flat grid 512 (XCD-swizzled), block 512 (8 waves): M=256 x N=64 px.
// q=0 -> raw f32 sums into d_out; q=1 -> raw f16 sums into part1h (ws).
// Window: 8 rows x 64 cols x 32ch f16 (32 KB), swizzled. 3 taps/iteration.
// Sampling interpolation in PACKED f16 (half8).
// ---------------------------------------------------------------------------
__global__ __launch_bounds__(512) void k_main(
    const float* __restrict__ x, const float* __restrict__ om_part,
    const float* __restrict__ b_off, const unsigned short* __restrict__ wt2,
    float* __restrict__ outr, unsigned short* __restrict__ part1h) {

    const int wgid = blockIdx.x;                       // 0..511
    const int swz  = ((wgid & 7) << 6) + (wgid >> 3);  // XCD-contiguous
    const int q = swz & 1;                             // K half
    const int h = (swz >> 1) & 63;
    const int b = swz >> 7;
    const int tid  = threadIdx.x;
    const int lane = tid & 63;
    const int wid  = tid >> 6;

    __shared__ ushort4v sidx2[576];        // packed corners or sentinel
    __shared__ ushort4v sw4[576];          // f16 corner weights (mask folded)
    __shared__ _Float16 S[2][3][4][64][8]; // [buf][tap-in-triple][g][px][8k]
    __shared__ _Float16 xw[WPIX * 32];     // [pix 512][32ch] f16, swizzled

    // ---- stage 0: bilinear params per (tap,px) -----------------------------
    for (int j = tid; j < 576; j += 512) {
        const int k  = j >> 6;
        const int px = j & 63;
        const int sp = (h << 6) + px;
        float oy = b_off[k], ox = b_off[k + KK], mz = b_off[k + 2 * KK];
#pragma unroll
        for (int qq = 0; qq < QOFF; ++qq) {
            const float* bp = om_part + (size_t)((qq * BB + b) * 27) * 4096 + sp;
            oy += bp[k * 4096];
            ox += bp[(k + KK) * 4096];
            mz += bp[(k + 2 * KK) * 4096];
        }
        const float mask = 1.f / (1.f + expf(-mz));
        const float py  = (float)h  - 1.f + (float)(k / 3) + oy;
        const float pxc = (float)px - 1.f + (float)(k % 3) + ox;
        const float y0f = floorf(py), x0f = floorf(pxc);
        const float ly = py - y0f, lx = pxc - x0f;
        const int y0 = (int)y0f, x0 = (int)x0f;

        float w00, w01, w10, w11;
        {
            bool v = (y0 >= 0) && (y0 < HH) && (x0 >= 0) && (x0 < WWD);
            w00 = v ? (1.f - ly) * (1.f - lx) * mask : 0.f;
        }
        {
            bool v = (y0 >= 0) && (y0 < HH) && (x0 + 1 < WWD) && (x0 + 1 >= 0);
            w01 = v ? (1.f - ly) * lx * mask : 0.f;
        }
        {
            bool v = (y0 + 1 >= 0) && (y0 + 1 < HH) && (x0 >= 0) && (x0 < WWD);
            w10 = v ? ly * (1.f - lx) * mask : 0.f;
        }
        {
            bool v = (y0 + 1 >= 0) && (y0 + 1 < HH) && (x0 + 1 >= 0) && (x0 + 1 < WWD);
            w11 = v ? ly * lx * mask : 0.f;
        }
        const int cy0 = min(max(y0, 0), 63),     cy1 = min(max(y0 + 1, 0), 63);
        const int cx0 = min(max(x0, 0), 63),     cx1 = min(max(x0 + 1, 0), 63);
        const int li0 = cy0 - (h - 3),           li1 = cy1 - (h - 3);
        ushort4v pv;
        if ((unsigned)li0 < (unsigned)WROWS && (unsigned)li1 < (unsigned)WROWS) {
            const int p00 = (li0 << 6) + cx0, p01 = (li0 << 6) + cx1;
            const int p10 = (li1 << 6) + cx0, p11 = (li1 << 6) + cx1;
            pv.x = (unsigned short)((p00 << 6) | ((p00 + (p00 >> 2)) & 3));
            pv.y = (unsigned short)((p01 << 6) | ((p01 + (p01 >> 2)) & 3));
            pv.z = (unsigned short)((p10 << 6) | ((p10 + (p10 >> 2)) & 3));
            pv.w = (unsigned short)((p11 << 6) | ((p11 + (p11 >> 2)) & 3));
        } else {                       // window miss -> global fallback
            pv.x = 0xFFFFu;
            pv.y = (unsigned short)(y0 + 32);
            pv.z = (unsigned short)(x0 + 32);
            pv.w = 0;
        }
        ushort4v wv;
        wv.x = f2hbits(w00);
        wv.y = f2hbits(w01);
        wv.z = f2hbits(w10);
        wv.w = f2hbits(w11);
        sidx2[j] = pv;
        sw4[j]   = wv;
    }

    const float* xb = x + ((size_t)b << 20);

    // ---- window staging (sync): [pix 512][32ch] f16, swizzled --------------
    auto STAGE = [&](int chunk) {
#pragma unroll
        for (int r4 = 0; r4 < 4; ++r4) {
            const int t   = r4 * 512 + tid;          // 0..2047
            const int g   = t >> 9;                  // 0..3 (8-ch group)
            const int pix = t & 511;
            const int wr  = pix >> 6, col = pix & 63;
            const int gro = (min(max(h - 3 + wr, 0), 63) << 6) + col;
            const float* xc = xb + ((size_t)((chunk << 5) + (g << 3)) << 12) + gro;
            float a[8];
#pragma unroll
            for (int j = 0; j < 8; ++j) a[j] = xc[(size_t)j << 12];
            const int pos = (g + pix + (pix >> 2)) & 3;
            *(half8*)&xw[pix * 32 + pos * 8] = pack8h(a);
        }
    };

    // ---- sampling task: 8 channels, packed-f16 interpolation ---------------
    auto TASK = [&](int c2, int sub2, int t, int buf2) {
        const int tp   = t >> 8;                 // tap within triple (0..2)
        const int slot = t & 255;
        const int g  = slot >> 6;
        const int px = slot & 63;
        const int tap = sub2 * 3 + tp;           // local tap 0..8
        const int j = (tap << 6) + px;
        const ushort4v sv = sidx2[j];
        const ushort4v wv = sw4[j];
        if (sv.x != 0xFFFFu) {
            const int o0 = ((sv.x & 0xFFC0u) >> 1) + (((sv.x + g) & 3u) << 3);
            const int o1 = ((sv.y & 0xFFC0u) >> 1) + (((sv.y + g) & 3u) << 3);
            const int o2 = ((sv.z & 0xFFC0u) >> 1) + (((sv.z + g) & 3u) << 3);
            const int o3 = ((sv.w & 0xFFC0u) >> 1) + (((sv.w + g) & 3u) << 3);
            const half8 c00 = *(const half8*)&xw[o0];
            const half8 c01 = *(const half8*)&xw[o1];
            const half8 c10 = *(const half8*)&xw[o2];
            const half8 c11 = *(const half8*)&xw[o3];
            half8 a8 = c00 * h_from_bits(wv.x) + c01 * h_from_bits(wv.y)
                     + c10 * h_from_bits(wv.z) + c11 * h_from_bits(wv.w);
            *(half8*)&S[buf2][tp][g][px][0] = a8;
        } else {                             // global fallback (rare)
            const float w00 = (float)h_from_bits(wv.x);
            const float w01 = (float)h_from_bits(wv.y);
            const float w10 = (float)h_from_bits(wv.z);
            const float w11 = (float)h_from_bits(wv.w);
            const int y0 = (int)sv.y - 32, x0 = (int)sv.z - 32;
            const int cy0 = min(max(y0, 0), 63), cy1 = min(max(y0 + 1, 0), 63);
            const int cx0 = min(max(x0, 0), 63), cx1 = min(max(x0 + 1, 0), 63);
            const int i00 = (cy0 << 6) + cx0, i01 = (cy0 << 6) + cx1;
            const int i10 = (cy1 << 6) + cx0, i11 = (cy1 << 6) + cx1;
            const float* xc = xb + ((size_t)((c2 << 5) + (g << 3)) << 12);
            float a[8];
#pragma unroll
            for (int j2 = 0; j2 < 8; ++j2) {
                a[j2] = w00 * xc[i00] + w01 * xc[i01]
                      + w10 * xc[i10] + w11 * xc[i11];
                xc += 4096;
            }
            *(half8*)&S[buf2][tp][g][px][0] = pack8h(a);
        }
    };
    // 768 tasks over 512 threads: every thread one, waves 0-3 a second.
    auto SAMPLE3 = [&](int c2, int sub2, int buf2) {
        TASK(c2, sub2, tid, buf2);
        if (tid < 256) TASK(c2, sub2, 512 + tid, buf2);
    };

    // A-frag: wave wid owns rows wid*32..+31; lane row=(lane&15), k=(lane>>4)*8+j
    const unsigned short* wbase = wt2 + ((wid * 32 + (lane & 15)) << 5)
                                      + ((lane >> 4) << 3);
    const int bpx = lane & 15;
    const int bg  = lane >> 4;

    float4v acc[2][4];
#pragma unroll
    for (int mt = 0; mt < 2; ++mt)
#pragma unroll
        for (int nt = 0; nt < 4; ++nt) acc[mt][nt] = (float4v){0.f, 0.f, 0.f, 0.f};

    const int c0 = q * 4;                 // this block's chunk range [c0, c0+4)

    __syncthreads();             // params ready
    STAGE(c0);
    __syncthreads();             // window chunk c0 ready
    SAMPLE3(c0, 0, 0);           // taps 0,1,2 -> S[0]
    __syncthreads();             // S[0] ready

    // ---- main loop: 12 iterations (3 taps each) ----------------------------
    int c = c0, sub = 0;
#pragma unroll 1
    for (int it = 0; it < NIT3; ++it) {
        const int sbase = c * 9 + sub * 3;
        const half8 a00 = *(const half8*)(wbase + (size_t)sbase * 8192);
        const half8 a01 = *(const half8*)(wbase + (size_t)sbase * 8192 + 512);
        const half8 a10 = *(const half8*)(wbase + (size_t)(sbase + 1) * 8192);
        const half8 a11 = *(const half8*)(wbase + (size_t)(sbase + 1) * 8192 + 512);
        const half8 a20 = *(const half8*)(wbase + (size_t)(sbase + 2) * 8192);
        const half8 a21 = *(const half8*)(wbase + (size_t)(sbase + 2) * 8192 + 512);

        const int buf = it & 1;
        __builtin_amdgcn_s_setprio(1);
        {
            const _Float16* Sb = &S[buf][0][bg][bpx][0];
            half8 b0 = *(const half8*)(Sb);
            half8 b1 = *(const half8*)(Sb + 128);
            half8 b2 = *(const half8*)(Sb + 256);
            half8 b3 = *(const half8*)(Sb + 384);
            acc[0][0] = __builtin_amdgcn_mfma_f32_16x16x32_f16(a00, b0, acc[0][0], 0, 0, 0);
            acc[0][1] = __builtin_amdgcn_mfma_f32_16x16x32_f16(a00, b1, acc[0][1], 0, 0, 0);
            acc[0][2] = __builtin_amdgcn_mfma_f32_16x16x32_f16(a00, b2, acc[0][2], 0, 0, 0);
            acc[0][3] = __builtin_amdgcn_mfma_f32_16x16x32_f16(a00, b3, acc[0][3], 0, 0, 0);
            acc[1][0] = __builtin_amdgcn_mfma_f32_16x16x32_f16(a01, b0, acc[1][0], 0, 0, 0);
            acc[1][1] = __builtin_amdgcn_mfma_f32_16x16x32_f16(a01, b1, acc[1][1], 0, 0, 0);
            acc[1][2] = __builtin_amdgcn_mfma_f32_16x16x32_f16(a01, b2, acc[1][2], 0, 0, 0);
            acc[1][3] = __builtin_amdgcn_mfma_f32_16x16x32_f16(a01, b3, acc[1][3], 0, 0, 0);
        }
        {
            const _Float16* Sb = &S[buf][1][bg][bpx][0];
            half8 b0 = *(const half8*)(Sb);
            half8 b1 = *(const half8*)(Sb + 128);
            half8 b2 = *(const half8*)(Sb + 256);
            half8 b3 = *(const half8*)(Sb + 384);
            acc[0][0] = __builtin_amdgcn_mfma_f32_16x16x32_f16(a10, b0, acc[0][0], 0, 0, 0);
            acc[0][1] = __builtin_amdgcn_mfma_f32_16x16x32_f16(a10, b1, acc[0][1], 0, 0, 0);
            acc[0][2] = __builtin_amdgcn_mfma_f32_16x16x32_f16(a10, b2, acc[0][2], 0, 0, 0);
            acc[0][3] = __builtin_amdgcn_mfma_f32_16x16x32_f16(a10, b3, acc[0][3], 0, 0, 0);
            acc[1][0] = __builtin_amdgcn_mfma_f32_16x16x32_f16(a11, b0, acc[1][0], 0, 0, 0);
            acc[1][1] = __builtin_amdgcn_mfma_f32_16x16x32_f16(a11, b1, acc[1][1], 0, 0, 0);
            acc[1][2] = __builtin_amdgcn_mfma_f32_16x16x32_f16(a11, b2, acc[1][2], 0, 0, 0);
            acc[1][3] = __builtin_amdgcn_mfma_f32_16x16x32_f16(a11, b3, acc[1][3], 0, 0, 0);
        }
        {
            const _Float16* Sb = &S[buf][2][bg][bpx][0];
            half8 b0 = *(const half8*)(Sb);
            half8 b1 = *(const half8*)(Sb + 128);
            half8 b2 = *(const half8*)(Sb + 256);
            half8 b3 = *(const half8*)(Sb + 384);
            acc[0][0] = __builtin_amdgcn_mfma_f32_16x16x32_f16(a20, b0, acc[0][0], 0, 0, 0);
            acc[0][1] = __builtin_amdgcn_mfma_f32_16x16x32_f16(a20, b1, acc[0][1], 0, 0, 0);
            acc[0][2] = __builtin_amdgcn_mfma_f32_16x16x32_f16(a20, b2, acc[0][2], 0, 0, 0);
            acc[0][3] = __builtin_amdgcn_mfma_f32_16x16x32_f16(a20, b3, acc[0][3], 0, 0, 0);
            acc[1][0] = __builtin_amdgcn_mfma_f32_16x16x32_f16(a21, b0, acc[1][0], 0, 0, 0);
            acc[1][1] = __builtin_amdgcn_mfma_f32_16x16x32_f16(a21, b1, acc[1][1], 0, 0, 0);
            acc[1][2] = __builtin_amdgcn_mfma_f32_16x16x32_f16(a21, b2, acc[1][2], 0, 0, 0);
            acc[1][3] = __builtin_amdgcn_mfma_f32_16x16x32_f16(a21, b3, acc[1][3], 0, 0, 0);
        }
        __builtin_amdgcn_s_setprio(0);

        if (it + 1 < NIT3) {
            int subn = sub + 1, cn = c;
            if (subn == 3) { subn = 0; cn = c + 1; }
            if (subn == 0) {                     // next iter samples new chunk
                STAGE(cn);
                __syncthreads();                 // window cn ready
            }
            SAMPLE3(cn, subn, (it + 1) & 1);
            c = cn; sub = subn;
        }
        __syncthreads();
    }

    // ---- epilogue: raw partial sums; D layout col=lane&15, row=(lane>>4)*4+r
    const int r4 = lane >> 4;
    if (q == 0) {
        float* ob = outr + (((size_t)b * 256) << 12) + (h << 6);
#pragma unroll
        for (int mt = 0; mt < 2; ++mt)
#pragma unroll
            for (int nt = 0; nt < 4; ++nt) {
                const int px = nt * 16 + bpx;
#pragma unroll
                for (int r = 0; r < 4; ++r) {
                    const int o = wid * 32 + mt * 16 + r4 * 4 + r;
                    ob[((size_t)o << 12) + px] = acc[mt][nt][r];
                }
            }
    } else {
        unsigned short* ob = part1h + (((size_t)b * 256) << 12) + (h << 6);
#pragma unroll
        for (int mt = 0; mt < 2; ++mt)
#pragma unroll
            for (int nt = 0; nt < 4; ++nt) {
                const int px = nt * 16 + bpx;
#pragma unroll
                for (int r = 0; r < 4; ++r) {
                    const int o = wid * 32 + mt * 16 + r4 * 4 + r;
                    ob[((size_t)o << 12) + px] = f2hbits(acc[mt][nt][r]);
                }
            }
    }
}

// ---------------------------------------------------------------------------
// Kernel 3: out += f16 partial; bias + BN + ReLU, in-place on d_out. float4.
// ---------------------------------------------------------------------------
__global__ __launch_bounds__(256) void k_bn(const unsigned short* __restrict__ part1h,
                                            const float* __restrict__ bias,
                                            const float* __restrict__ gamma,
                                            const float* __restrict__ beta,
                                            const float* __restrict__ rmean,
                                            const float* __restrict__ rvar,
                                            float* __restrict__ out) {
    const int NTOT4 = BB * OUTC * 4096 / 4;          // 1,048,576 float4
    int i = blockIdx.x * 256 + threadIdx.x;
    const int stride = gridDim.x * 256;
#pragma unroll 1
    for (; i < NTOT4; i += stride) {
        const int e0 = i << 2;
        const int o  = (e0 >> 12) & 255;             // channel (wave-uniform)
        const float inv = gamma[o] * rsqrtf(rvar[o] + 1e-5f);
        const float sh  = beta[o] - rmean[o] * inv + bias[o] * inv;
        float4 a = ((const float4*)out)[i];
        ushort4v p = ((const ushort4v*)part1h)[i];
        float4 v;
        v.x = fmaxf((a.x + (float)h_from_bits(p.x)) * inv + sh, 0.f);
        v.y = fmaxf((a.y + (float)h_from_bits(p.y)) * inv + sh, 0.f);
        v.z = fmaxf((a.z + (float)h_from_bits(p.z)) * inv + sh, 0.f);
        v.w = fmaxf((a.w + (float)h_from_bits(p.w)) * inv + sh, 0.f);
        ((float4*)out)[i] = v;
    }
}

// ---------------------------------------------------------------------------
extern "C" void kernel_launch(void* const* d_in, const int* in_sizes, int n_in,
                              void* d_out, int out_size, void* d_ws, size_t ws_size,
                              hipStream_t stream) {
    const float* x     = (const float*)d_in[0];
    const float* w_off = (const float*)d_in[1];
    const float* b_off = (const float*)d_in[2];
    const float* w     = (const float*)d_in[3];
    const float* bias  = (const float*)d_in[4];
    const float* gamma = (const float*)d_in[5];
    const float* beta  = (const float*)d_in[6];
    const float* rmean = (const float*)d_in[7];
    const float* rvar  = (const float*)d_in[8];
    float* out = (float*)d_out;

    float* om_part = (float*)d_ws;                                  // 4*4*27*4096 f32
    unsigned short* wt2 = (unsigned short*)(om_part + QOFF * BB * 27 * 4096);
    unsigned short* wo2 = wt2 + 72 * 256 * 32;                      // 72*32*32 f16
    unsigned short* part1h = wo2 + 72 * 32 * 32;                    // 4*256*4096 f16

    k_packs<<<2592, 256, 0, stream>>>(w, w_off, wt2, wo2);
    k_off_mfma<<<1024, 256, 0, stream>>>(x, wo2, om_part);
    k_main<<<512, 512, 0, stream>>>(x, om_part, b_off, wt2, out, part1h);
    k_bn<<<2048, 256, 0, stream>>>(part1h, bias, gamma, beta, rmean, rvar, out);
}